// Round 6
// baseline (997.886 us; speedup 1.0000x reference)
//
#include <hip/hip_runtime.h>
#include <cmath>

typedef unsigned short u16;
typedef unsigned int   u32;
typedef __attribute__((ext_vector_type(8))) short bf16x8;
typedef __attribute__((ext_vector_type(4))) float f32x4;
typedef __attribute__((ext_vector_type(4))) u32   u32x4;

__device__ __forceinline__ float bf2f(u16 u){
    union { u32 i; float f; } x; x.i = ((u32)u) << 16; return x.f;
}
__device__ __forceinline__ u16 f2bf(float f){
    union { float f; u32 i; } x; x.f = f;
    u32 r = x.i + 0x7fffu + ((x.i >> 16) & 1u);
    return (u16)(r >> 16);
}

// ---------------- graph preprocessing ----------------

__global__ void k_count(const int* __restrict__ src, const int* __restrict__ dst,
                        int* cnt, int* notsink, int* pos, int E){
    int e = blockIdx.x*256 + threadIdx.x;
    if (e < E){
        pos[e] = atomicAdd(&cnt[dst[e]], 1);
        notsink[src[e]] = 1;   // benign race: all writers store 1
    }
}

__global__ void k_scan1(const int* __restrict__ in, int* blocksum, int N){
    __shared__ int sh[256];
    int tid = threadIdx.x;
    int base = blockIdx.x*1024 + tid*4;
    int s = 0;
    for (int j=0;j<4;j++){ int i = base+j; s += (i < N) ? in[i] : 0; }
    sh[tid] = s; __syncthreads();
    for (int d=128; d>0; d>>=1){ if (tid < d) sh[tid] += sh[tid+d]; __syncthreads(); }
    if (tid == 0) blocksum[blockIdx.x] = sh[0];
}

__global__ void k_scan2(int* blocksum, int nb){
    if (threadIdx.x == 0){
        int run = 0;
        for (int i=0;i<nb;i++){ int v = blocksum[i]; blocksum[i] = run; run += v; }
    }
}

__global__ void k_scan3(const int* __restrict__ in, const int* __restrict__ blockoff,
                        int* out, float* inv_deg, float* haspred, int N){
    __shared__ int sh[256];
    int tid = threadIdx.x;
    int base = blockIdx.x*1024 + tid*4;
    int e[4]; int s = 0;
    for (int j=0;j<4;j++){ int i = base+j; e[j] = (i < N) ? in[i] : 0; s += e[j]; }
    sh[tid] = s; __syncthreads();
    for (int d=1; d<256; d<<=1){
        int t = (tid >= d) ? sh[tid-d] : 0;
        __syncthreads();
        sh[tid] += t;
        __syncthreads();
    }
    int excl = sh[tid] - s + blockoff[blockIdx.x];
    for (int j=0;j<4;j++){
        int i = base+j;
        if (i < N){
            out[i] = excl; excl += e[j];
            inv_deg[i] = 1.0f / (float)(e[j] > 1 ? e[j] : 1);
            haspred[i] = e[j] > 0 ? 1.0f : 0.0f;
        }
    }
}

__global__ void k_place(const int* __restrict__ src, const int* __restrict__ dst,
                        const int* __restrict__ row_ptr, const int* __restrict__ pos,
                        int* csr_src, int E){
    int e = blockIdx.x*256 + threadIdx.x;
    if (e < E)
        csr_src[row_ptr[dst[e]] + pos[e]] = src[e];
}

// transpose+convert weight matrices: f32 [K][128] -> bf16 [128][K]; shift = log2(K*128)
__global__ void k_wt(const float* __restrict__ in, u16* __restrict__ out,
                     int shift, int K, int total){
    int i = blockIdx.x*256 + threadIdx.x;
    if (i < total){
        int mat = i >> shift;
        int within = i & ((1 << shift) - 1);
        int k = within >> 7, n = within & 127;
        out[(size_t)mat*(K*128) + n*K + k] = f2bf(in[i]);
    }
}

// ---------------- GEMM: h0 = f32 feats @ W_in + b_in -> bf16 ----------------

__global__ __launch_bounds__(256) void k_gemm_in(
    const float* __restrict__ A, const u16* __restrict__ BT,
    const float* __restrict__ bias, u16* __restrict__ C, int n_rows)
{
    __shared__ u16 lA[64][136];
    int tid = threadIdx.x, wave = tid >> 6, lane = tid & 63;
    int sl = lane & 15, g16 = lane >> 4;
    int row0 = blockIdx.x * 64;
    f32x4 acc[8];
    #pragma unroll
    for (int t=0;t<8;t++) acc[t] = (f32x4){0.f,0.f,0.f,0.f};

    #pragma unroll
    for (int i=0;i<4;i++){
        int c = i*256 + tid;
        int r = c >> 4, col8 = (c & 15) * 8;
        u16 o[8] = {0,0,0,0,0,0,0,0};
        if (row0 + r < n_rows){
            float4 v0 = *(const float4*)(A + (size_t)(row0 + r)*128 + col8);
            float4 v1 = *(const float4*)(A + (size_t)(row0 + r)*128 + col8 + 4);
            o[0]=f2bf(v0.x); o[1]=f2bf(v0.y); o[2]=f2bf(v0.z); o[3]=f2bf(v0.w);
            o[4]=f2bf(v1.x); o[5]=f2bf(v1.y); o[6]=f2bf(v1.z); o[7]=f2bf(v1.w);
        }
        *(u32x4*)&lA[r][col8] = *(const u32x4*)o;
    }
    __syncthreads();
    #pragma unroll
    for (int kk=0;kk<4;kk++){
        int ka = kk*32 + g16*8;
        bf16x8 a = *(const bf16x8*)&lA[wave*16 + sl][ka];
        #pragma unroll
        for (int t=0;t<8;t++){
            bf16x8 b = *(const bf16x8*)(BT + (size_t)(t*16 + sl)*128 + ka);
            acc[t] = __builtin_amdgcn_mfma_f32_16x16x32_bf16(a, b, acc[t], 0, 0, 0);
        }
    }

    int rbase = wave*16 + g16*4;
    float bc[8];
    #pragma unroll
    for (int t=0;t<8;t++) bc[t] = bias[t*16 + sl];
    for (int r=0;r<4;r++){
        int row = row0 + rbase + r;
        if (row >= n_rows) continue;
        #pragma unroll
        for (int t=0;t<8;t++)
            C[(size_t)row*128 + t*16 + sl] = f2bf(acc[t][r] + bc[t]);
    }
}

// -------- fused layer, WAVE-LOCAL (zero __syncthreads):
//   each wave owns 16 rows: stage h, gather neigh-mean, M = h@Ws+bs+hp*(ng@Wn+bn),
//   g = sigmoid([h,M]@Wg+bg), v = g*M+(1-g)*h, LayerNorm, ReLU.
//   B fragments loaded straight from global (L2-hot weights), no LDS B-staging. --------

__global__ __launch_bounds__(256, 4) void k_layer(
    const u16* __restrict__ H,
    const int* __restrict__ row_ptr, const int* __restrict__ indeg,
    const float* __restrict__ inv_deg, const int* __restrict__ csr_src,
    const u16* __restrict__ BsT, const u16* __restrict__ BnT,
    const u16* __restrict__ BgT,
    const float* __restrict__ bs, const float* __restrict__ bn,
    const float* __restrict__ bg,
    const float* __restrict__ gamma, const float* __restrict__ beta,
    const float* __restrict__ haspred,
    u16* __restrict__ Hb, float* __restrict__ Hf, int n_rows)
{
    __shared__ u16 lA[4][16][136];   // per-wave h tile
    __shared__ u16 lM[4][16][136];   // per-wave gathered-neigh tile, then M tile
    int tid = threadIdx.x, wave = tid >> 6, lane = tid & 63;
    int sl = lane & 15, g16 = lane >> 4;
    int row0 = blockIdx.x*64 + wave*16;   // this wave's 16 rows

    // stage own 16 h rows (wave-local, coalesced 16B)
    #pragma unroll
    for (int i=0;i<4;i++){
        int c = i*64 + lane;
        int r = c >> 4, col8 = (c & 15) * 8;
        u32x4 v = {0,0,0,0};
        if (row0 + r < n_rows)
            v = *(const u32x4*)(H + (size_t)(row0 + r)*128 + col8);
        *(u32x4*)&lA[wave][r][col8] = v;
    }

    // gather predecessor mean into own lM rows (16 lanes per node)
    #pragma unroll
    for (int pass=0; pass<4; pass++){
        int r = pass*4 + g16;
        int node = row0 + r;
        if (node < n_rows){
            float acc[8] = {0.f,0.f,0.f,0.f,0.f,0.f,0.f,0.f};
            int deg = indeg[node], start = row_ptr[node];
            for (int e0 = 0; e0 < deg; e0 += 16){   // deg uniform within 16-lane group
                int idx = (e0 + sl < deg) ? csr_src[start + e0 + sl] : 0;
                int c = deg - e0;
                #pragma unroll
                for (int j = 0; j < 16; j++){
                    int sidx = __shfl(idx, (g16 << 4) | j);
                    if (j < c){
                        bf16x8 v = *(const bf16x8*)(H + (size_t)sidx*128 + sl*8);
                        #pragma unroll
                        for (int t=0;t<8;t++) acc[t] += bf2f((u16)v[t]);
                    }
                }
            }
            float iv = inv_deg[node];
            u16 o[8];
            #pragma unroll
            for (int t=0;t<8;t++) o[t] = f2bf(acc[t]*iv);
            *(u32x4*)&lM[wave][r][sl*8] = *(const u32x4*)o;
        } else {
            u32x4 z = {0,0,0,0};
            *(u32x4*)&lM[wave][r][sl*8] = z;
        }
    }

    f32x4 accs[8], accn[8];
    #pragma unroll
    for (int t=0;t<8;t++){ accs[t] = (f32x4){0.f,0.f,0.f,0.f}; accn[t] = (f32x4){0.f,0.f,0.f,0.f}; }

    // phase 1+2: h @ Ws, ng @ Wn  (B direct from global)
    #pragma unroll
    for (int kk=0;kk<4;kk++){
        int ka = kk*32 + g16*8;
        bf16x8 a = *(const bf16x8*)&lA[wave][sl][ka];
        bf16x8 m = *(const bf16x8*)&lM[wave][sl][ka];
        #pragma unroll
        for (int t=0;t<8;t++){
            bf16x8 b1 = *(const bf16x8*)(BsT + (size_t)(t*16 + sl)*128 + ka);
            accs[t] = __builtin_amdgcn_mfma_f32_16x16x32_bf16(a, b1, accs[t], 0, 0, 0);
            bf16x8 b2 = *(const bf16x8*)(BnT + (size_t)(t*16 + sl)*128 + ka);
            accn[t] = __builtin_amdgcn_mfma_f32_16x16x32_bf16(m, b2, accn[t], 0, 0, 0);
        }
    }

    // build M in own lM rows (C-layout write; wave-local)
    int rloc = g16*4;
    {
        float bsc[8], bnc[8];
        #pragma unroll
        for (int t=0;t<8;t++){ bsc[t] = bs[t*16 + sl]; bnc[t] = bn[t*16 + sl]; }
        #pragma unroll
        for (int r=0;r<4;r++){
            int row = row0 + rloc + r;
            float hp = (row < n_rows) ? haspred[row] : 0.f;
            #pragma unroll
            for (int t=0;t<8;t++){
                float m = accs[t][r] + bsc[t] + hp*(accn[t][r] + bnc[t]);
                lM[wave][rloc + r][t*16 + sl] = f2bf(m);
            }
        }
    }

    // phase 3: gate = h @ Wg_top + M @ Wg_bot  (reuse accs)
    #pragma unroll
    for (int t=0;t<8;t++) accs[t] = (f32x4){0.f,0.f,0.f,0.f};
    #pragma unroll
    for (int kk=0;kk<4;kk++){
        int ka = kk*32 + g16*8;
        bf16x8 a = *(const bf16x8*)&lA[wave][sl][ka];
        #pragma unroll
        for (int t=0;t<8;t++){
            bf16x8 b = *(const bf16x8*)(BgT + (size_t)(t*16 + sl)*256 + ka);
            accs[t] = __builtin_amdgcn_mfma_f32_16x16x32_bf16(a, b, accs[t], 0, 0, 0);
        }
    }
    #pragma unroll
    for (int kk=0;kk<4;kk++){
        int ka = kk*32 + g16*8;
        bf16x8 m = *(const bf16x8*)&lM[wave][sl][ka];
        #pragma unroll
        for (int t=0;t<8;t++){
            bf16x8 b = *(const bf16x8*)(BgT + (size_t)(t*16 + sl)*256 + 128 + ka);
            accs[t] = __builtin_amdgcn_mfma_f32_16x16x32_bf16(m, b, accs[t], 0, 0, 0);
        }
    }

    // epilogue: gate, blend, LayerNorm, ReLU (16-lane-group reductions)
    float bgc[8], gam[8], bet[8];
    #pragma unroll
    for (int t=0;t<8;t++){
        int col = t*16 + sl;
        bgc[t] = bg[col]; gam[t] = gamma[col]; bet[t] = beta[col];
    }
    for (int r=0;r<4;r++){
        int row = row0 + rloc + r;
        if (row >= n_rows) continue;   // group-uniform
        float v[8], s = 0.f;
        #pragma unroll
        for (int t=0;t<8;t++){
            int col = t*16 + sl;
            float x = accs[t][r] + bgc[t];
            float gg = 1.f/(1.f + expf(-x));
            float hv = bf2f(lA[wave][rloc + r][col]);
            float mv = bf2f(lM[wave][rloc + r][col]);
            v[t] = gg*mv + (1.f - gg)*hv;
            s += v[t];
        }
        s += __shfl_xor(s,1); s += __shfl_xor(s,2); s += __shfl_xor(s,4); s += __shfl_xor(s,8);
        float mu = s * (1.f/128.f);
        float q = 0.f;
        #pragma unroll
        for (int t=0;t<8;t++){ float d = v[t]-mu; q += d*d; }
        q += __shfl_xor(q,1); q += __shfl_xor(q,2); q += __shfl_xor(q,4); q += __shfl_xor(q,8);
        float rs = rsqrtf(q*(1.f/128.f) + 1e-5f);
        #pragma unroll
        for (int t=0;t<8;t++){
            size_t idx = (size_t)row*128 + t*16 + sl;
            float o = (v[t]-mu)*rs*gam[t] + bet[t];
            o = o > 0.f ? o : 0.f;
            if (Hb) Hb[idx] = f2bf(o);
            if (Hf) Hf[idx] = o;
        }
    }
}

// ------- GEMM: scores = sinkmask( tanh(h@W_att+b_att) @ W_score + b_score ) -------

__global__ __launch_bounds__(256) void k_gemm_att(
    const float* __restrict__ H, const u16* __restrict__ BT,
    const float* __restrict__ b_att, const float* __restrict__ Wsc,
    const float* __restrict__ bsc, const int* __restrict__ notsink,
    float* __restrict__ scores, int n_rows)
{
    __shared__ u16 lA[64][136];
    int tid = threadIdx.x, wave = tid >> 6, lane = tid & 63;
    int sl = lane & 15, g16 = lane >> 4;
    int row0 = blockIdx.x * 64;
    f32x4 acc[8];
    #pragma unroll
    for (int t=0;t<8;t++) acc[t] = (f32x4){0.f,0.f,0.f,0.f};

    #pragma unroll
    for (int i=0;i<4;i++){
        int c = i*256 + tid;
        int r = c >> 4, col8 = (c & 15) * 8;
        u16 o[8] = {0,0,0,0,0,0,0,0};
        if (row0 + r < n_rows){
            float4 v0 = *(const float4*)(H + (size_t)(row0 + r)*128 + col8);
            float4 v1 = *(const float4*)(H + (size_t)(row0 + r)*128 + col8 + 4);
            o[0]=f2bf(v0.x); o[1]=f2bf(v0.y); o[2]=f2bf(v0.z); o[3]=f2bf(v0.w);
            o[4]=f2bf(v1.x); o[5]=f2bf(v1.y); o[6]=f2bf(v1.z); o[7]=f2bf(v1.w);
        }
        *(u32x4*)&lA[r][col8] = *(const u32x4*)o;
    }
    __syncthreads();
    #pragma unroll
    for (int kk=0;kk<4;kk++){
        int ka = kk*32 + g16*8;
        bf16x8 a = *(const bf16x8*)&lA[wave*16 + sl][ka];
        #pragma unroll
        for (int t=0;t<8;t++){
            bf16x8 b = *(const bf16x8*)(BT + (size_t)(t*16 + sl)*128 + ka);
            acc[t] = __builtin_amdgcn_mfma_f32_16x16x32_bf16(a, b, acc[t], 0, 0, 0);
        }
    }

    int rbase = wave*16 + g16*4;
    float bac[8], wc[8];
    #pragma unroll
    for (int t=0;t<8;t++){ bac[t] = b_att[t*16 + sl]; wc[t] = Wsc[t*16 + sl]; }
    float b0 = bsc[0];
    for (int r=0;r<4;r++){
        int row = row0 + rbase + r;
        if (row >= n_rows) continue;
        float p = 0.f;
        #pragma unroll
        for (int t=0;t<8;t++) p += tanhf(acc[t][r] + bac[t]) * wc[t];
        p += __shfl_xor(p,1); p += __shfl_xor(p,2); p += __shfl_xor(p,4); p += __shfl_xor(p,8);
        if (sl == 0)
            scores[row] = (notsink[row] == 0) ? (p + b0) : -INFINITY;
    }
}

// ---------------- softmax-pool over sinks (no max: |score| <= ~5) ----------------

__global__ void k_pool1(const float* __restrict__ h, const float* __restrict__ scores,
                        float* accum, float* part, int N){
    __shared__ float sh[256];
    __shared__ float sw[256];
    int tid = threadIdx.x;
    int col = tid & 127, grp = tid >> 7;
    float acc = 0.f, wsum = 0.f;
    for (int n = blockIdx.x*2 + grp; n < N; n += 512){
        float s = scores[n];
        if (s > -1e30f){
            float w = expf(s);
            acc += w * h[(size_t)n*128 + col];
            if (col == 0) wsum += w;
        }
    }
    sh[tid] = acc; sw[tid] = wsum; __syncthreads();
    if (tid < 128) sw[tid] += sw[tid+128];
    __syncthreads();
    for (int d=64; d>0; d>>=1){ if (tid < d) sw[tid] += sw[tid+d]; __syncthreads(); }
    if (tid < 128) atomicAdd(&accum[col], sh[tid] + sh[tid+128]);
    if (tid == 0) part[blockIdx.x] = sw[0];
}

__global__ void k_pool2(const float* __restrict__ part, const float* __restrict__ accum,
                        float* __restrict__ out){
    __shared__ float sh[256];
    int tid = threadIdx.x;
    sh[tid] = part[tid]; __syncthreads();
    for (int d=128; d>0; d>>=1){ if (tid < d) sh[tid] += sh[tid+d]; __syncthreads(); }
    if (tid < 128) out[tid] = accum[tid] / sh[0];
}

// ---------------- host launch ----------------

extern "C" void kernel_launch(void* const* d_in, const int* in_sizes, int n_in,
                              void* d_out, int out_size, void* d_ws, size_t ws_size,
                              hipStream_t stream)
{
    const float* node_feats = (const float*)d_in[0];
    const int* src     = (const int*)d_in[1];
    const int* dst     = (const int*)d_in[2];
    const float* W_in    = (const float*)d_in[3];
    const float* b_in    = (const float*)d_in[4];
    const float* Ws      = (const float*)d_in[5];
    const float* bs      = (const float*)d_in[6];
    const float* Wn      = (const float*)d_in[7];
    const float* bn      = (const float*)d_in[8];
    const float* Wg      = (const float*)d_in[9];
    const float* bg      = (const float*)d_in[10];
    const float* gamma   = (const float*)d_in[11];
    const float* beta    = (const float*)d_in[12];
    const float* W_att   = (const float*)d_in[13];
    const float* b_att   = (const float*)d_in[14];
    const float* W_score = (const float*)d_in[15];
    const float* b_score = (const float*)d_in[16];

    const int N = in_sizes[0] / 128;
    const int E = in_sizes[1];

    char* w = (char*)d_ws;
    auto alloc = [&](size_t bytes)->char* {
        char* p = w; w += (bytes + 255) & ~(size_t)255; return p;
    };
    u16* WT_in  = (u16*)alloc(128*128*2);
    u16* WT_s   = (u16*)alloc(3*128*128*2);
    u16* WT_n   = (u16*)alloc(3*128*128*2);
    u16* WT_g   = (u16*)alloc(3*128*256*2);
    u16* WT_att = (u16*)alloc(128*128*2);
    // zeroed region: cnt, notsink, emb_accum (contiguous)
    int* cnt      = (int*)alloc((size_t)N*4);
    int* notsink  = (int*)alloc((size_t)N*4);
    float* emb_accum = (float*)alloc(128*4);
    size_t zero_bytes = (size_t)((char*)(emb_accum + 128) - (char*)cnt);
    int* pos      = (int*)alloc((size_t)E*4);
    int* row_ptr  = (int*)alloc((size_t)N*4);
    int* blocksum = (int*)alloc(1024*4);
    int* csr_src  = (int*)alloc((size_t)E*4);
    float* inv_deg = (float*)alloc((size_t)N*4);
    float* haspred = (float*)alloc((size_t)N*4);
    float* scores  = (float*)alloc((size_t)N*4);
    float* part    = (float*)alloc(256*4);
    u16* buf0 = (u16*)alloc((size_t)N*128*2);   // h ping
    u16* buf1 = (u16*)alloc((size_t)N*128*2);   // h pong

    float* h_out   = (float*)d_out;
    float* emb_out = h_out + (size_t)N*128;

    hipMemsetAsync(cnt, 0, zero_bytes, stream);

    k_wt<<<(16384+255)/256, 256, 0, stream>>>(W_in,  WT_in,  14, 128, 16384);
    k_wt<<<(49152+255)/256, 256, 0, stream>>>(Ws,    WT_s,   14, 128, 49152);
    k_wt<<<(49152+255)/256, 256, 0, stream>>>(Wn,    WT_n,   14, 128, 49152);
    k_wt<<<(98304+255)/256, 256, 0, stream>>>(Wg,    WT_g,   15, 256, 98304);
    k_wt<<<(16384+255)/256, 256, 0, stream>>>(W_att, WT_att, 14, 128, 16384);

    k_count<<<(E+255)/256, 256, 0, stream>>>(src, dst, cnt, notsink, pos, E);

    int nb = (N + 1023) / 1024;
    k_scan1<<<nb, 256, 0, stream>>>(cnt, blocksum, N);
    k_scan2<<<1, 256, 0, stream>>>(blocksum, nb);
    k_scan3<<<nb, 256, 0, stream>>>(cnt, blocksum, row_ptr, inv_deg, haspred, N);
    k_place<<<(E+255)/256, 256, 0, stream>>>(src, dst, row_ptr, pos, csr_src, E);

    int gblk = (N + 63) / 64;

    k_gemm_in<<<gblk, 256, 0, stream>>>(node_feats, WT_in, b_in, buf0, N);

    u16* hin = buf0;
    for (int i=0;i<3;i++){
        u16* hb  = (i == 2) ? nullptr : ((hin == buf0) ? buf1 : buf0);
        float* hf = (i == 2) ? h_out : nullptr;
        k_layer<<<gblk, 256, 0, stream>>>(hin, row_ptr, cnt, inv_deg, csr_src,
                                          WT_s + i*16384, WT_n + i*16384, WT_g + i*32768,
                                          bs + i*128, bn + i*128, bg + i*128,
                                          gamma + i*128, beta + i*128, haspred,
                                          hb, hf, N);
        if (i < 2) hin = hb;
    }

    k_gemm_att<<<gblk, 256, 0, stream>>>(h_out, WT_att, b_att, W_score, b_score,
                                         notsink, scores, N);
    k_pool1<<<256, 256, 0, stream>>>(h_out, scores, emb_accum, part, N);
    k_pool2<<<1, 256, 0, stream>>>(part, emb_accum, emb_out);

    (void)n_in; (void)out_size; (void)ws_size;
}

// Round 7
// 954.239 us; speedup vs baseline: 1.0457x; 1.0457x over previous
//
#include <hip/hip_runtime.h>
#include <cmath>

typedef unsigned short u16;
typedef unsigned int   u32;
typedef __attribute__((ext_vector_type(8))) short bf16x8;
typedef __attribute__((ext_vector_type(4))) float f32x4;
typedef __attribute__((ext_vector_type(4))) u32   u32x4;

__device__ __forceinline__ float bf2f(u16 u){
    union { u32 i; float f; } x; x.i = ((u32)u) << 16; return x.f;
}
__device__ __forceinline__ u16 f2bf(float f){
    union { float f; u32 i; } x; x.f = f;
    u32 r = x.i + 0x7fffu + ((x.i >> 16) & 1u);
    return (u16)(r >> 16);
}

// ---------------- graph preprocessing ----------------

__global__ void k_count(const int* __restrict__ src, const int* __restrict__ dst,
                        int* cnt, int* notsink, int* pos, int E){
    int e = blockIdx.x*256 + threadIdx.x;
    if (e < E){
        pos[e] = atomicAdd(&cnt[dst[e]], 1);
        notsink[src[e]] = 1;   // benign race: all writers store 1
    }
}

__global__ void k_scan1(const int* __restrict__ in, int* blocksum, int N){
    __shared__ int sh[256];
    int tid = threadIdx.x;
    int base = blockIdx.x*1024 + tid*4;
    int s = 0;
    for (int j=0;j<4;j++){ int i = base+j; s += (i < N) ? in[i] : 0; }
    sh[tid] = s; __syncthreads();
    for (int d=128; d>0; d>>=1){ if (tid < d) sh[tid] += sh[tid+d]; __syncthreads(); }
    if (tid == 0) blocksum[blockIdx.x] = sh[0];
}

__global__ void k_scan2(int* blocksum, int nb){
    if (threadIdx.x == 0){
        int run = 0;
        for (int i=0;i<nb;i++){ int v = blocksum[i]; blocksum[i] = run; run += v; }
    }
}

__global__ void k_scan3(const int* __restrict__ in, const int* __restrict__ blockoff,
                        int* out, float* inv_deg, float* haspred, int N){
    __shared__ int sh[256];
    int tid = threadIdx.x;
    int base = blockIdx.x*1024 + tid*4;
    int e[4]; int s = 0;
    for (int j=0;j<4;j++){ int i = base+j; e[j] = (i < N) ? in[i] : 0; s += e[j]; }
    sh[tid] = s; __syncthreads();
    for (int d=1; d<256; d<<=1){
        int t = (tid >= d) ? sh[tid-d] : 0;
        __syncthreads();
        sh[tid] += t;
        __syncthreads();
    }
    int excl = sh[tid] - s + blockoff[blockIdx.x];
    for (int j=0;j<4;j++){
        int i = base+j;
        if (i < N){
            out[i] = excl; excl += e[j];
            inv_deg[i] = 1.0f / (float)(e[j] > 1 ? e[j] : 1);
            haspred[i] = e[j] > 0 ? 1.0f : 0.0f;
        }
    }
}

__global__ void k_place(const int* __restrict__ src, const int* __restrict__ dst,
                        const int* __restrict__ row_ptr, const int* __restrict__ pos,
                        int* csr_src, int E){
    int e = blockIdx.x*256 + threadIdx.x;
    if (e < E)
        csr_src[row_ptr[dst[e]] + pos[e]] = src[e];
}

// transpose+convert weight matrices: f32 [K][128] -> bf16 [128][K]; shift = log2(K*128)
__global__ void k_wt(const float* __restrict__ in, u16* __restrict__ out,
                     int shift, int K, int total){
    int i = blockIdx.x*256 + threadIdx.x;
    if (i < total){
        int mat = i >> shift;
        int within = i & ((1 << shift) - 1);
        int k = within >> 7, n = within & 127;
        out[(size_t)mat*(K*128) + n*K + k] = f2bf(in[i]);
    }
}

// ------- neighbor mean: 2 nodes per 16-lane group (interleaved for 2x MLP) -------

__global__ __launch_bounds__(256) void k_neigh(
    const u16* __restrict__ h, const int* __restrict__ row_ptr,
    const int* __restrict__ indeg, const float* __restrict__ inv_deg,
    const int* __restrict__ csr_src, u16* __restrict__ neigh, int N)
{
    int gid  = (blockIdx.x*256 + threadIdx.x) >> 4;   // global 16-lane group id
    int sl   = threadIdx.x & 15;
    int gbase = (threadIdx.x & 63) & 48;              // group's base lane in wave
    int nA = gid*2, nB = gid*2 + 1;
    bool vA = nA < N, vB = nB < N;
    int degA = vA ? indeg[nA] : 0, startA = vA ? row_ptr[nA] : 0;
    int degB = vB ? indeg[nB] : 0, startB = vB ? row_ptr[nB] : 0;
    float accA[8] = {0,0,0,0,0,0,0,0};
    float accB[8] = {0,0,0,0,0,0,0,0};
    int maxd = degA > degB ? degA : degB;
    for (int e0 = 0; e0 < maxd; e0 += 16){            // uniform within the group
        int idxA = (e0 + sl < degA) ? csr_src[startA + e0 + sl] : 0;
        int idxB = (e0 + sl < degB) ? csr_src[startB + e0 + sl] : 0;
        int cA = degA - e0, cB = degB - e0;
        #pragma unroll
        for (int j = 0; j < 16; j++){
            int sA = __shfl(idxA, gbase + j);
            int sB = __shfl(idxB, gbase + j);
            if (j < cA){
                bf16x8 v = *(const bf16x8*)(h + (size_t)sA*128 + sl*8);
                #pragma unroll
                for (int t=0;t<8;t++) accA[t] += bf2f((u16)v[t]);
            }
            if (j < cB){
                bf16x8 v = *(const bf16x8*)(h + (size_t)sB*128 + sl*8);
                #pragma unroll
                for (int t=0;t<8;t++) accB[t] += bf2f((u16)v[t]);
            }
        }
    }
    if (vA){
        float iv = inv_deg[nA];
        u16 o[8];
        #pragma unroll
        for (int t=0;t<8;t++) o[t] = f2bf(accA[t]*iv);
        *(u32x4*)(neigh + (size_t)nA*128 + sl*8) = *(const u32x4*)o;
    }
    if (vB){
        float iv = inv_deg[nB];
        u16 o[8];
        #pragma unroll
        for (int t=0;t<8;t++) o[t] = f2bf(accB[t]*iv);
        *(u32x4*)(neigh + (size_t)nB*128 + sl*8) = *(const u32x4*)o;
    }
}

// ---------------- GEMM: h0 = f32 feats @ W_in + b_in -> bf16 ----------------

__global__ __launch_bounds__(256) void k_gemm_in(
    const float* __restrict__ A, const u16* __restrict__ BT,
    const float* __restrict__ bias, u16* __restrict__ C, int n_rows)
{
    __shared__ u16 lA[64][136];
    int tid = threadIdx.x, wave = tid >> 6, lane = tid & 63;
    int sl = lane & 15, g16 = lane >> 4;
    int row0 = blockIdx.x * 64;
    f32x4 acc[8];
    #pragma unroll
    for (int t=0;t<8;t++) acc[t] = (f32x4){0.f,0.f,0.f,0.f};

    #pragma unroll
    for (int i=0;i<4;i++){
        int c = i*256 + tid;
        int r = c >> 4, col8 = (c & 15) * 8;
        u16 o[8] = {0,0,0,0,0,0,0,0};
        if (row0 + r < n_rows){
            float4 v0 = *(const float4*)(A + (size_t)(row0 + r)*128 + col8);
            float4 v1 = *(const float4*)(A + (size_t)(row0 + r)*128 + col8 + 4);
            o[0]=f2bf(v0.x); o[1]=f2bf(v0.y); o[2]=f2bf(v0.z); o[3]=f2bf(v0.w);
            o[4]=f2bf(v1.x); o[5]=f2bf(v1.y); o[6]=f2bf(v1.z); o[7]=f2bf(v1.w);
        }
        *(u32x4*)&lA[r][col8] = *(const u32x4*)o;
    }
    __syncthreads();
    #pragma unroll
    for (int kk=0;kk<4;kk++){
        int ka = kk*32 + g16*8;
        bf16x8 a = *(const bf16x8*)&lA[wave*16 + sl][ka];
        #pragma unroll
        for (int t=0;t<8;t++){
            bf16x8 b = *(const bf16x8*)(BT + (size_t)(t*16 + sl)*128 + ka);
            acc[t] = __builtin_amdgcn_mfma_f32_16x16x32_bf16(a, b, acc[t], 0, 0, 0);
        }
    }

    int rbase = wave*16 + g16*4;
    float bc[8];
    #pragma unroll
    for (int t=0;t<8;t++) bc[t] = bias[t*16 + sl];
    for (int r=0;r<4;r++){
        int row = row0 + rbase + r;
        if (row >= n_rows) continue;
        #pragma unroll
        for (int t=0;t<8;t++)
            C[(size_t)row*128 + t*16 + sl] = f2bf(acc[t][r] + bc[t]);
    }
}

// -------- fused layer, WAVE-LOCAL (zero __syncthreads), gather-free:
//   each wave owns 16 rows: stage h + neigh, M = h@Ws+bs+hp*(ng@Wn+bn),
//   g = sigmoid([h,M]@Wg+bg), v = g*M+(1-g)*h, LayerNorm, ReLU.
//   B fragments loaded straight from global (L2-hot weights). --------

__global__ __launch_bounds__(256, 4) void k_layer(
    const u16* __restrict__ H, const u16* __restrict__ Ng,
    const u16* __restrict__ BsT, const u16* __restrict__ BnT,
    const u16* __restrict__ BgT,
    const float* __restrict__ bs, const float* __restrict__ bn,
    const float* __restrict__ bg,
    const float* __restrict__ gamma, const float* __restrict__ beta,
    const float* __restrict__ haspred,
    u16* __restrict__ Hb, float* __restrict__ Hf, int n_rows)
{
    __shared__ u16 lA[4][16][136];   // per-wave h tile
    __shared__ u16 lM[4][16][136];   // per-wave neigh tile, then M tile
    int tid = threadIdx.x, wave = tid >> 6, lane = tid & 63;
    int sl = lane & 15, g16 = lane >> 4;
    int row0 = blockIdx.x*64 + wave*16;   // this wave's 16 rows

    // stage own 16 h rows and 16 neigh rows (wave-local, coalesced 16B)
    #pragma unroll
    for (int i=0;i<4;i++){
        int c = i*64 + lane;
        int r = c >> 4, col8 = (c & 15) * 8;
        u32x4 v = {0,0,0,0}, n = {0,0,0,0};
        if (row0 + r < n_rows){
            v = *(const u32x4*)(H  + (size_t)(row0 + r)*128 + col8);
            n = *(const u32x4*)(Ng + (size_t)(row0 + r)*128 + col8);
        }
        *(u32x4*)&lA[wave][r][col8] = v;
        *(u32x4*)&lM[wave][r][col8] = n;
    }

    f32x4 accs[8], accn[8];
    #pragma unroll
    for (int t=0;t<8;t++){ accs[t] = (f32x4){0.f,0.f,0.f,0.f}; accn[t] = (f32x4){0.f,0.f,0.f,0.f}; }

    // phase 1+2: h @ Ws, ng @ Wn  (B direct from global)
    #pragma unroll
    for (int kk=0;kk<4;kk++){
        int ka = kk*32 + g16*8;
        bf16x8 a = *(const bf16x8*)&lA[wave][sl][ka];
        bf16x8 m = *(const bf16x8*)&lM[wave][sl][ka];
        #pragma unroll
        for (int t=0;t<8;t++){
            bf16x8 b1 = *(const bf16x8*)(BsT + (size_t)(t*16 + sl)*128 + ka);
            accs[t] = __builtin_amdgcn_mfma_f32_16x16x32_bf16(a, b1, accs[t], 0, 0, 0);
            bf16x8 b2 = *(const bf16x8*)(BnT + (size_t)(t*16 + sl)*128 + ka);
            accn[t] = __builtin_amdgcn_mfma_f32_16x16x32_bf16(m, b2, accn[t], 0, 0, 0);
        }
    }

    // build M in own lM rows (C-layout write; wave-local)
    int rloc = g16*4;
    {
        float bsc[8], bnc[8];
        #pragma unroll
        for (int t=0;t<8;t++){ bsc[t] = bs[t*16 + sl]; bnc[t] = bn[t*16 + sl]; }
        #pragma unroll
        for (int r=0;r<4;r++){
            int row = row0 + rloc + r;
            float hp = (row < n_rows) ? haspred[row] : 0.f;
            #pragma unroll
            for (int t=0;t<8;t++){
                float m = accs[t][r] + bsc[t] + hp*(accn[t][r] + bnc[t]);
                lM[wave][rloc + r][t*16 + sl] = f2bf(m);
            }
        }
    }

    // phase 3: gate = h @ Wg_top + M @ Wg_bot  (reuse accs)
    #pragma unroll
    for (int t=0;t<8;t++) accs[t] = (f32x4){0.f,0.f,0.f,0.f};
    #pragma unroll
    for (int kk=0;kk<4;kk++){
        int ka = kk*32 + g16*8;
        bf16x8 a = *(const bf16x8*)&lA[wave][sl][ka];
        #pragma unroll
        for (int t=0;t<8;t++){
            bf16x8 b = *(const bf16x8*)(BgT + (size_t)(t*16 + sl)*256 + ka);
            accs[t] = __builtin_amdgcn_mfma_f32_16x16x32_bf16(a, b, accs[t], 0, 0, 0);
        }
    }
    #pragma unroll
    for (int kk=0;kk<4;kk++){
        int ka = kk*32 + g16*8;
        bf16x8 m = *(const bf16x8*)&lM[wave][sl][ka];
        #pragma unroll
        for (int t=0;t<8;t++){
            bf16x8 b = *(const bf16x8*)(BgT + (size_t)(t*16 + sl)*256 + 128 + ka);
            accs[t] = __builtin_amdgcn_mfma_f32_16x16x32_bf16(m, b, accs[t], 0, 0, 0);
        }
    }

    // epilogue: gate, blend, LayerNorm, ReLU (16-lane-group reductions)
    float bgc[8], gam[8], bet[8];
    #pragma unroll
    for (int t=0;t<8;t++){
        int col = t*16 + sl;
        bgc[t] = bg[col]; gam[t] = gamma[col]; bet[t] = beta[col];
    }
    for (int r=0;r<4;r++){
        int row = row0 + rloc + r;
        if (row >= n_rows) continue;   // group-uniform
        float v[8], s = 0.f;
        #pragma unroll
        for (int t=0;t<8;t++){
            int col = t*16 + sl;
            float x = accs[t][r] + bgc[t];
            float gg = 1.f/(1.f + expf(-x));
            float hv = bf2f(lA[wave][rloc + r][col]);
            float mv = bf2f(lM[wave][rloc + r][col]);
            v[t] = gg*mv + (1.f - gg)*hv;
            s += v[t];
        }
        s += __shfl_xor(s,1); s += __shfl_xor(s,2); s += __shfl_xor(s,4); s += __shfl_xor(s,8);
        float mu = s * (1.f/128.f);
        float q = 0.f;
        #pragma unroll
        for (int t=0;t<8;t++){ float d = v[t]-mu; q += d*d; }
        q += __shfl_xor(q,1); q += __shfl_xor(q,2); q += __shfl_xor(q,4); q += __shfl_xor(q,8);
        float rs = rsqrtf(q*(1.f/128.f) + 1e-5f);
        #pragma unroll
        for (int t=0;t<8;t++){
            size_t idx = (size_t)row*128 + t*16 + sl;
            float o = (v[t]-mu)*rs*gam[t] + bet[t];
            o = o > 0.f ? o : 0.f;
            if (Hb) Hb[idx] = f2bf(o);
            if (Hf) Hf[idx] = o;
        }
    }
}

// ------- GEMM: scores = sinkmask( tanh(h@W_att+b_att) @ W_score + b_score ) -------

__global__ __launch_bounds__(256) void k_gemm_att(
    const float* __restrict__ H, const u16* __restrict__ BT,
    const float* __restrict__ b_att, const float* __restrict__ Wsc,
    const float* __restrict__ bsc, const int* __restrict__ notsink,
    float* __restrict__ scores, int n_rows)
{
    __shared__ u16 lA[64][136];
    int tid = threadIdx.x, wave = tid >> 6, lane = tid & 63;
    int sl = lane & 15, g16 = lane >> 4;
    int row0 = blockIdx.x * 64;
    f32x4 acc[8];
    #pragma unroll
    for (int t=0;t<8;t++) acc[t] = (f32x4){0.f,0.f,0.f,0.f};

    #pragma unroll
    for (int i=0;i<4;i++){
        int c = i*256 + tid;
        int r = c >> 4, col8 = (c & 15) * 8;
        u16 o[8] = {0,0,0,0,0,0,0,0};
        if (row0 + r < n_rows){
            float4 v0 = *(const float4*)(H + (size_t)(row0 + r)*128 + col8);
            float4 v1 = *(const float4*)(H + (size_t)(row0 + r)*128 + col8 + 4);
            o[0]=f2bf(v0.x); o[1]=f2bf(v0.y); o[2]=f2bf(v0.z); o[3]=f2bf(v0.w);
            o[4]=f2bf(v1.x); o[5]=f2bf(v1.y); o[6]=f2bf(v1.z); o[7]=f2bf(v1.w);
        }
        *(u32x4*)&lA[r][col8] = *(const u32x4*)o;
    }
    __syncthreads();
    #pragma unroll
    for (int kk=0;kk<4;kk++){
        int ka = kk*32 + g16*8;
        bf16x8 a = *(const bf16x8*)&lA[wave*16 + sl][ka];
        #pragma unroll
        for (int t=0;t<8;t++){
            bf16x8 b = *(const bf16x8*)(BT + (size_t)(t*16 + sl)*128 + ka);
            acc[t] = __builtin_amdgcn_mfma_f32_16x16x32_bf16(a, b, acc[t], 0, 0, 0);
        }
    }

    int rbase = wave*16 + g16*4;
    float bac[8], wc[8];
    #pragma unroll
    for (int t=0;t<8;t++){ bac[t] = b_att[t*16 + sl]; wc[t] = Wsc[t*16 + sl]; }
    float b0 = bsc[0];
    for (int r=0;r<4;r++){
        int row = row0 + rbase + r;
        if (row >= n_rows) continue;
        float p = 0.f;
        #pragma unroll
        for (int t=0;t<8;t++) p += tanhf(acc[t][r] + bac[t]) * wc[t];
        p += __shfl_xor(p,1); p += __shfl_xor(p,2); p += __shfl_xor(p,4); p += __shfl_xor(p,8);
        if (sl == 0)
            scores[row] = (notsink[row] == 0) ? (p + b0) : -INFINITY;
    }
}

// ---------------- softmax-pool over sinks (no max: |score| <= ~5) ----------------

__global__ void k_pool1(const float* __restrict__ h, const float* __restrict__ scores,
                        float* accum, float* part, int N){
    __shared__ float sh[256];
    __shared__ float sw[256];
    int tid = threadIdx.x;
    int col = tid & 127, grp = tid >> 7;
    float acc = 0.f, wsum = 0.f;
    for (int n = blockIdx.x*2 + grp; n < N; n += 512){
        float s = scores[n];
        if (s > -1e30f){
            float w = expf(s);
            acc += w * h[(size_t)n*128 + col];
            if (col == 0) wsum += w;
        }
    }
    sh[tid] = acc; sw[tid] = wsum; __syncthreads();
    if (tid < 128) sw[tid] += sw[tid+128];
    __syncthreads();
    for (int d=64; d>0; d>>=1){ if (tid < d) sw[tid] += sw[tid+d]; __syncthreads(); }
    if (tid < 128) atomicAdd(&accum[col], sh[tid] + sh[tid+128]);
    if (tid == 0) part[blockIdx.x] = sw[0];
}

__global__ void k_pool2(const float* __restrict__ part, const float* __restrict__ accum,
                        float* __restrict__ out){
    __shared__ float sh[256];
    int tid = threadIdx.x;
    sh[tid] = part[tid]; __syncthreads();
    for (int d=128; d>0; d>>=1){ if (tid < d) sh[tid] += sh[tid+d]; __syncthreads(); }
    if (tid < 128) out[tid] = accum[tid] / sh[0];
}

// ---------------- host launch ----------------

extern "C" void kernel_launch(void* const* d_in, const int* in_sizes, int n_in,
                              void* d_out, int out_size, void* d_ws, size_t ws_size,
                              hipStream_t stream)
{
    const float* node_feats = (const float*)d_in[0];
    const int* src     = (const int*)d_in[1];
    const int* dst     = (const int*)d_in[2];
    const float* W_in    = (const float*)d_in[3];
    const float* b_in    = (const float*)d_in[4];
    const float* Ws      = (const float*)d_in[5];
    const float* bs      = (const float*)d_in[6];
    const float* Wn      = (const float*)d_in[7];
    const float* bn      = (const float*)d_in[8];
    const float* Wg      = (const float*)d_in[9];
    const float* bg      = (const float*)d_in[10];
    const float* gamma   = (const float*)d_in[11];
    const float* beta    = (const float*)d_in[12];
    const float* W_att   = (const float*)d_in[13];
    const float* b_att   = (const float*)d_in[14];
    const float* W_score = (const float*)d_in[15];
    const float* b_score = (const float*)d_in[16];

    const int N = in_sizes[0] / 128;
    const int E = in_sizes[1];

    char* w = (char*)d_ws;
    auto alloc = [&](size_t bytes)->char* {
        char* p = w; w += (bytes + 255) & ~(size_t)255; return p;
    };
    u16* WT_in  = (u16*)alloc(128*128*2);
    u16* WT_s   = (u16*)alloc(3*128*128*2);
    u16* WT_n   = (u16*)alloc(3*128*128*2);
    u16* WT_g   = (u16*)alloc(3*128*256*2);
    u16* WT_att = (u16*)alloc(128*128*2);
    // zeroed region: cnt, notsink, emb_accum (contiguous)
    int* cnt      = (int*)alloc((size_t)N*4);
    int* notsink  = (int*)alloc((size_t)N*4);
    float* emb_accum = (float*)alloc(128*4);
    size_t zero_bytes = (size_t)((char*)(emb_accum + 128) - (char*)cnt);
    int* pos      = (int*)alloc((size_t)E*4);
    int* row_ptr  = (int*)alloc((size_t)N*4);
    int* blocksum = (int*)alloc(1024*4);
    int* csr_src  = (int*)alloc((size_t)E*4);
    float* inv_deg = (float*)alloc((size_t)N*4);
    float* haspred = (float*)alloc((size_t)N*4);
    float* scores  = (float*)alloc((size_t)N*4);
    float* part    = (float*)alloc(256*4);
    u16* buf0 = (u16*)alloc((size_t)N*128*2);   // h ping
    u16* buf1 = (u16*)alloc((size_t)N*128*2);   // h pong
    u16* bufn = (u16*)alloc((size_t)N*128*2);   // neigh

    float* h_out   = (float*)d_out;
    float* emb_out = h_out + (size_t)N*128;

    hipMemsetAsync(cnt, 0, zero_bytes, stream);

    k_wt<<<(16384+255)/256, 256, 0, stream>>>(W_in,  WT_in,  14, 128, 16384);
    k_wt<<<(49152+255)/256, 256, 0, stream>>>(Ws,    WT_s,   14, 128, 49152);
    k_wt<<<(49152+255)/256, 256, 0, stream>>>(Wn,    WT_n,   14, 128, 49152);
    k_wt<<<(98304+255)/256, 256, 0, stream>>>(Wg,    WT_g,   15, 256, 98304);
    k_wt<<<(16384+255)/256, 256, 0, stream>>>(W_att, WT_att, 14, 128, 16384);

    k_count<<<(E+255)/256, 256, 0, stream>>>(src, dst, cnt, notsink, pos, E);

    int nb = (N + 1023) / 1024;
    k_scan1<<<nb, 256, 0, stream>>>(cnt, blocksum, N);
    k_scan2<<<1, 256, 0, stream>>>(blocksum, nb);
    k_scan3<<<nb, 256, 0, stream>>>(cnt, blocksum, row_ptr, inv_deg, haspred, N);
    k_place<<<(E+255)/256, 256, 0, stream>>>(src, dst, row_ptr, pos, csr_src, E);

    int gblk = (N + 63) / 64;
    int nblk = (N + 31) / 32;   // k_neigh: 32 nodes per block (16 groups x 2)

    k_gemm_in<<<gblk, 256, 0, stream>>>(node_feats, WT_in, b_in, buf0, N);

    u16* hin = buf0;
    for (int i=0;i<3;i++){
        k_neigh<<<nblk, 256, 0, stream>>>(hin, row_ptr, cnt, inv_deg, csr_src, bufn, N);
        u16* hb  = (i == 2) ? nullptr : ((hin == buf0) ? buf1 : buf0);
        float* hf = (i == 2) ? h_out : nullptr;
        k_layer<<<gblk, 256, 0, stream>>>(hin, bufn,
                                          WT_s + i*16384, WT_n + i*16384, WT_g + i*32768,
                                          bs + i*128, bn + i*128, bg + i*128,
                                          gamma + i*128, beta + i*128, haspred,
                                          hb, hf, N);
        if (i < 2) hin = hb;
    }

    k_gemm_att<<<gblk, 256, 0, stream>>>(h_out, WT_att, b_att, W_score, b_score,
                                         notsink, scores, N);
    k_pool1<<<256, 256, 0, stream>>>(h_out, scores, emb_accum, part, N);
    k_pool2<<<1, 256, 0, stream>>>(part, emb_accum, emb_out);

    (void)n_in; (void)out_size; (void)ws_size;
}

// Round 8
// 622.400 us; speedup vs baseline: 1.6033x; 1.5332x over previous
//
#include <hip/hip_runtime.h>
#include <cmath>

typedef unsigned short u16;
typedef unsigned int   u32;
typedef __attribute__((ext_vector_type(8))) short bf16x8;
typedef __attribute__((ext_vector_type(4))) float f32x4;
typedef __attribute__((ext_vector_type(4))) u32   u32x4;

__device__ __forceinline__ float bf2f(u16 u){
    union { u32 i; float f; } x; x.i = ((u32)u) << 16; return x.f;
}
__device__ __forceinline__ u16 f2bf(float f){
    union { float f; u32 i; } x; x.f = f;
    u32 r = x.i + 0x7fffu + ((x.i >> 16) & 1u);
    return (u16)(r >> 16);
}

// ---------------- graph preprocessing ----------------

__global__ void k_count(const int* __restrict__ src, const int* __restrict__ dst,
                        int* cnt, int* notsink, int* pos, int E){
    int e = blockIdx.x*256 + threadIdx.x;
    if (e < E){
        pos[e] = atomicAdd(&cnt[dst[e]], 1);
        notsink[src[e]] = 1;   // benign race: all writers store 1
    }
}

__global__ void k_scan1(const int* __restrict__ in, int* blocksum, int N){
    __shared__ int sh[256];
    int tid = threadIdx.x;
    int base = blockIdx.x*1024 + tid*4;
    int s = 0;
    for (int j=0;j<4;j++){ int i = base+j; s += (i < N) ? in[i] : 0; }
    sh[tid] = s; __syncthreads();
    for (int d=128; d>0; d>>=1){ if (tid < d) sh[tid] += sh[tid+d]; __syncthreads(); }
    if (tid == 0) blocksum[blockIdx.x] = sh[0];
}

__global__ void k_scan2(int* blocksum, int nb){
    if (threadIdx.x == 0){
        int run = 0;
        for (int i=0;i<nb;i++){ int v = blocksum[i]; blocksum[i] = run; run += v; }
    }
}

__global__ void k_scan3(const int* __restrict__ in, const int* __restrict__ blockoff,
                        int* out, float* inv_deg, float* haspred, int N){
    __shared__ int sh[256];
    int tid = threadIdx.x;
    int base = blockIdx.x*1024 + tid*4;
    int e[4]; int s = 0;
    for (int j=0;j<4;j++){ int i = base+j; e[j] = (i < N) ? in[i] : 0; s += e[j]; }
    sh[tid] = s; __syncthreads();
    for (int d=1; d<256; d<<=1){
        int t = (tid >= d) ? sh[tid-d] : 0;
        __syncthreads();
        sh[tid] += t;
        __syncthreads();
    }
    int excl = sh[tid] - s + blockoff[blockIdx.x];
    for (int j=0;j<4;j++){
        int i = base+j;
        if (i < N){
            out[i] = excl; excl += e[j];
            inv_deg[i] = 1.0f / (float)(e[j] > 1 ? e[j] : 1);
            haspred[i] = e[j] > 0 ? 1.0f : 0.0f;
        }
    }
}

__global__ void k_place(const int* __restrict__ src, const int* __restrict__ dst,
                        const int* __restrict__ row_ptr, const int* __restrict__ pos,
                        int* csr_src, int E){
    int e = blockIdx.x*256 + threadIdx.x;
    if (e < E)
        csr_src[row_ptr[dst[e]] + pos[e]] = src[e];
}

// single-launch transpose+convert of all weight matrices: f32 [K][128] -> bf16 [128][K]
__global__ void k_wt_all(const float* __restrict__ W_in, const float* __restrict__ Ws,
                         const float* __restrict__ Wn, const float* __restrict__ Wg,
                         const float* __restrict__ W_att,
                         u16* WT_in, u16* WT_s, u16* WT_n, u16* WT_g, u16* WT_att){
    int i = blockIdx.x*256 + threadIdx.x;   // [0, 229376)
    const float* src; u16* dst; int shift, K, off;
    if (i < 16384)      { src=W_in;  dst=WT_in;  shift=14; K=128; off=i; }
    else if (i < 65536) { src=Ws;    dst=WT_s;   shift=14; K=128; off=i-16384; }
    else if (i < 114688){ src=Wn;    dst=WT_n;   shift=14; K=128; off=i-65536; }
    else if (i < 212992){ src=Wg;    dst=WT_g;   shift=15; K=256; off=i-114688; }
    else if (i < 229376){ src=W_att; dst=WT_att; shift=14; K=128; off=i-212992; }
    else return;
    int mat = off >> shift;
    int w = off & ((1 << shift) - 1);
    int k = w >> 7, n = w & 127;
    dst[(size_t)mat*(K*128) + n*K + k] = f2bf(src[off]);
}

// ---------------- neighbor mean: 4 nodes/wave, 16 lanes x 16B per row ----------------

__global__ void k_neigh(const u16* __restrict__ h, const int* __restrict__ row_ptr,
                        const int* __restrict__ indeg, const float* __restrict__ inv_deg,
                        const int* __restrict__ csr_src, u16* __restrict__ neigh, int N){
    int wid  = (blockIdx.x*256 + threadIdx.x) >> 6;
    int lane = threadIdx.x & 63;
    int sub = lane >> 4, sl = lane & 15;
    int node = wid*4 + sub;
    bool valid = node < N;
    int deg   = valid ? indeg[node]   : 0;
    int start = valid ? row_ptr[node] : 0;
    float acc[8] = {0.f,0.f,0.f,0.f,0.f,0.f,0.f,0.f};
    for (int e0 = 0; __any(e0 < deg); e0 += 16){
        int idx = 0;
        if (e0 + sl < deg) idx = csr_src[start + e0 + sl];
        int cnt = deg - e0;
        #pragma unroll
        for (int j = 0; j < 16; j++){
            int sidx = __shfl(idx, (sub << 4) | j);
            if (j < cnt){
                bf16x8 v = *(const bf16x8*)(h + (size_t)sidx*128 + sl*8);
                #pragma unroll
                for (int t=0;t<8;t++) acc[t] += bf2f((u16)v[t]);
            }
        }
    }
    if (valid){
        float iv = inv_deg[node];
        u16 o[8];
        #pragma unroll
        for (int t=0;t<8;t++) o[t] = f2bf(acc[t]*iv);
        *(u32x4*)(neigh + (size_t)node*128 + sl*8) = *(const u32x4*)o;
    }
}

// ---------------- shared GEMM tile machinery ----------------

__device__ __forceinline__ void stage_A_bf16(const u16* __restrict__ A, u16 (*lA)[136],
                                             int row0, int n_rows, int tid){
    #pragma unroll
    for (int i=0;i<4;i++){
        int c = i*256 + tid;
        int r = c >> 4, col8 = (c & 15) * 8;
        u32x4 v = {0,0,0,0};
        if (row0 + r < n_rows)
            v = *(const u32x4*)(A + (size_t)(row0 + r)*128 + col8);
        *(u32x4*)&lA[r][col8] = v;
    }
}

__device__ __forceinline__ void stage_A_f32(const float* __restrict__ A, u16 (*lA)[136],
                                            int row0, int n_rows, int tid){
    #pragma unroll
    for (int i=0;i<4;i++){
        int c = i*256 + tid;
        int r = c >> 4, col8 = (c & 15) * 8;
        u16 o[8] = {0,0,0,0,0,0,0,0};
        if (row0 + r < n_rows){
            float4 v0 = *(const float4*)(A + (size_t)(row0 + r)*128 + col8);
            float4 v1 = *(const float4*)(A + (size_t)(row0 + r)*128 + col8 + 4);
            o[0]=f2bf(v0.x); o[1]=f2bf(v0.y); o[2]=f2bf(v0.z); o[3]=f2bf(v0.w);
            o[4]=f2bf(v1.x); o[5]=f2bf(v1.y); o[6]=f2bf(v1.z); o[7]=f2bf(v1.w);
        }
        *(u32x4*)&lA[r][col8] = *(const u32x4*)o;
    }
}

// full-K B stage: 128 cols x 128 k
__device__ __forceinline__ void stage_B(const u16* __restrict__ BT, int Ks, int koff0,
                                        u16 (*lB)[136], int tid){
    #pragma unroll
    for (int i=0;i<8;i++){
        int c = i*256 + tid;
        int n = c >> 4, col8 = (c & 15) * 8;
        u32x4 v = *(const u32x4*)(BT + (size_t)n*Ks + koff0 + col8);
        *(u32x4*)&lB[n][col8] = v;
    }
}

// half-K B stage: 128 cols x 64 k window starting at koff0
__device__ __forceinline__ void stage_B_half(const u16* __restrict__ BT, int Ks, int koff0,
                                             u16 (*lB)[72], int tid){
    #pragma unroll
    for (int i=0;i<4;i++){
        int c = i*256 + tid;
        int n = c >> 3, col8 = (c & 7) * 8;
        *(u32x4*)&lB[n][col8] = *(const u32x4*)(BT + (size_t)n*Ks + koff0 + col8);
    }
}

__device__ __forceinline__ void mfma_tile(const u16 (*lA)[136], const u16 (*lB)[136],
                                          int wave, int lane, f32x4* acc){
    #pragma unroll
    for (int kk=0;kk<4;kk++){
        int koff = kk*32 + (lane >> 4) * 8;
        bf16x8 a = *(const bf16x8*)&lA[wave*16 + (lane & 15)][koff];
        #pragma unroll
        for (int t=0;t<8;t++){
            bf16x8 b = *(const bf16x8*)&lB[t*16 + (lane & 15)][koff];
            acc[t] = __builtin_amdgcn_mfma_f32_16x16x32_bf16(a, b, acc[t], 0, 0, 0);
        }
    }
}

__device__ __forceinline__ void mfma_half(const u16 (*lA)[136], const u16 (*lB)[72],
                                          int wave, int lane, int kbaseA, f32x4* acc){
    #pragma unroll
    for (int kk=0;kk<2;kk++){
        int kw = kk*32 + (lane >> 4) * 8;
        bf16x8 a = *(const bf16x8*)&lA[wave*16 + (lane & 15)][kbaseA + kw];
        #pragma unroll
        for (int t=0;t<8;t++){
            bf16x8 b = *(const bf16x8*)&lB[t*16 + (lane & 15)][kw];
            acc[t] = __builtin_amdgcn_mfma_f32_16x16x32_bf16(a, b, acc[t], 0, 0, 0);
        }
    }
}

// ---------------- GEMM: h0 = f32 feats @ W_in + b_in -> bf16 ----------------

__global__ __launch_bounds__(256) void k_gemm_in(
    const float* __restrict__ A, const u16* __restrict__ BT,
    const float* __restrict__ bias, u16* __restrict__ C, int n_rows)
{
    __shared__ u16 lA[64][136];
    __shared__ u16 lB[128][136];
    int tid = threadIdx.x, wave = tid >> 6, lane = tid & 63;
    int row0 = blockIdx.x * 64;
    f32x4 acc[8];
    #pragma unroll
    for (int t=0;t<8;t++) acc[t] = (f32x4){0.f,0.f,0.f,0.f};
    stage_A_f32(A, lA, row0, n_rows, tid);
    stage_B(BT, 128, 0, lB, tid);
    __syncthreads();
    mfma_tile(lA, lB, wave, lane, acc);

    int sl = lane & 15;
    int rbase = wave*16 + (lane >> 4)*4;
    float bc[8];
    #pragma unroll
    for (int t=0;t<8;t++) bc[t] = bias[t*16 + sl];
    for (int r=0;r<4;r++){
        int row = row0 + rbase + r;
        if (row >= n_rows) continue;
        #pragma unroll
        for (int t=0;t<8;t++)
            C[(size_t)row*128 + t*16 + sl] = f2bf(acc[t][r] + bc[t]);
    }
}

// -------- fused layer (round-4 proven structure): M = h@Ws+bs+hp*(ng@Wn+bn);
//          g = sigmoid([h,M]@Wg+bg); v = g*M+(1-g)*h; LayerNorm; ReLU --------

__global__ __launch_bounds__(256) void k_layer(
    const u16* __restrict__ H, const u16* __restrict__ Ng,
    const u16* __restrict__ BsT, const u16* __restrict__ BnT,
    const u16* __restrict__ BgT,
    const float* __restrict__ bs, const float* __restrict__ bn,
    const float* __restrict__ bg,
    const float* __restrict__ gamma, const float* __restrict__ beta,
    const float* __restrict__ haspred,
    u16* __restrict__ Hb, float* __restrict__ Hf, int n_rows)
{
    __shared__ u16 lA[64][136];   // H tile (persists whole kernel)
    __shared__ u16 lM[64][136];   // Ng tile, then M tile
    __shared__ u16 lB[128][72];   // half-K weight window
    int tid = threadIdx.x, wave = tid >> 6, lane = tid & 63;
    int sl = lane & 15, g16 = lane >> 4;
    int row0 = blockIdx.x * 64;
    f32x4 accs[8], accn[8];
    #pragma unroll
    for (int t=0;t<8;t++){ accs[t] = (f32x4){0.f,0.f,0.f,0.f}; accn[t] = (f32x4){0.f,0.f,0.f,0.f}; }

    // phase 1: h @ Ws
    stage_A_bf16(H, lA, row0, n_rows, tid);
    stage_B_half(BsT, 128, 0, lB, tid);
    __syncthreads();
    mfma_half(lA, lB, wave, lane, 0, accs);
    __syncthreads();
    stage_B_half(BsT, 128, 64, lB, tid);
    __syncthreads();
    mfma_half(lA, lB, wave, lane, 64, accs);
    __syncthreads();

    // phase 2: ng @ Wn
    stage_A_bf16(Ng, lM, row0, n_rows, tid);
    stage_B_half(BnT, 128, 0, lB, tid);
    __syncthreads();
    mfma_half(lM, lB, wave, lane, 0, accn);
    __syncthreads();
    stage_B_half(BnT, 128, 64, lB, tid);
    __syncthreads();
    mfma_half(lM, lB, wave, lane, 64, accn);
    __syncthreads();

    // build M in LDS (C-layout write; wave-local rows)
    int rbase = wave*16 + g16*4;
    {
        float bsc[8], bnc[8];
        #pragma unroll
        for (int t=0;t<8;t++){ bsc[t] = bs[t*16 + sl]; bnc[t] = bn[t*16 + sl]; }
        #pragma unroll
        for (int r=0;r<4;r++){
            int row = row0 + rbase + r;
            float hp = (row < n_rows) ? haspred[row] : 0.f;
            #pragma unroll
            for (int t=0;t<8;t++){
                float m = accs[t][r] + bsc[t] + hp*(accn[t][r] + bnc[t]);
                lM[rbase + r][t*16 + sl] = f2bf(m);
            }
        }
    }
    __syncthreads();

    // phase 3: gate = h @ Wg_top + M @ Wg_bot  (reuse accs)
    #pragma unroll
    for (int t=0;t<8;t++) accs[t] = (f32x4){0.f,0.f,0.f,0.f};
    stage_B_half(BgT, 256, 0, lB, tid);
    __syncthreads();
    mfma_half(lA, lB, wave, lane, 0, accs);
    __syncthreads();
    stage_B_half(BgT, 256, 64, lB, tid);
    __syncthreads();
    mfma_half(lA, lB, wave, lane, 64, accs);
    __syncthreads();
    stage_B_half(BgT, 256, 128, lB, tid);
    __syncthreads();
    mfma_half(lM, lB, wave, lane, 0, accs);
    __syncthreads();
    stage_B_half(BgT, 256, 192, lB, tid);
    __syncthreads();
    mfma_half(lM, lB, wave, lane, 64, accs);

    // epilogue: gate, blend, LayerNorm, ReLU (h and M from LDS)
    float bgc[8], gam[8], bet[8];
    #pragma unroll
    for (int t=0;t<8;t++){
        int col = t*16 + sl;
        bgc[t] = bg[col]; gam[t] = gamma[col]; bet[t] = beta[col];
    }
    for (int r=0;r<4;r++){
        int row = row0 + rbase + r;
        if (row >= n_rows) continue;   // quad-uniform
        float v[8], s = 0.f;
        #pragma unroll
        for (int t=0;t<8;t++){
            int col = t*16 + sl;
            float x = accs[t][r] + bgc[t];
            float gg = 1.f/(1.f + expf(-x));
            float hv = bf2f(lA[rbase + r][col]);
            float mv = bf2f(lM[rbase + r][col]);
            v[t] = gg*mv + (1.f - gg)*hv;
            s += v[t];
        }
        s += __shfl_xor(s,1); s += __shfl_xor(s,2); s += __shfl_xor(s,4); s += __shfl_xor(s,8);
        float mu = s * (1.f/128.f);
        float q = 0.f;
        #pragma unroll
        for (int t=0;t<8;t++){ float d = v[t]-mu; q += d*d; }
        q += __shfl_xor(q,1); q += __shfl_xor(q,2); q += __shfl_xor(q,4); q += __shfl_xor(q,8);
        float rs = rsqrtf(q*(1.f/128.f) + 1e-5f);
        #pragma unroll
        for (int t=0;t<8;t++){
            size_t idx = (size_t)row*128 + t*16 + sl;
            float o = (v[t]-mu)*rs*gam[t] + bet[t];
            o = o > 0.f ? o : 0.f;
            Hb[idx] = f2bf(o);
            if (Hf) Hf[idx] = o;
        }
    }
}

// ------- GEMM: scores = sinkmask( tanh(h@W_att+b_att) @ W_score + b_score ) -------

__global__ __launch_bounds__(256) void k_gemm_att(
    const u16* __restrict__ H, const u16* __restrict__ BT,
    const float* __restrict__ b_att, const float* __restrict__ Wsc,
    const float* __restrict__ bsc, const int* __restrict__ notsink,
    float* __restrict__ scores, int n_rows)
{
    __shared__ u16 lA[64][136];
    __shared__ u16 lB[128][136];
    int tid = threadIdx.x, wave = tid >> 6, lane = tid & 63;
    int row0 = blockIdx.x * 64;
    f32x4 acc[8];
    #pragma unroll
    for (int t=0;t<8;t++) acc[t] = (f32x4){0.f,0.f,0.f,0.f};
    stage_A_bf16(H, lA, row0, n_rows, tid);
    stage_B(BT, 128, 0, lB, tid);
    __syncthreads();
    mfma_tile(lA, lB, wave, lane, acc);

    int sl = lane & 15;
    int rbase = wave*16 + (lane >> 4)*4;
    float bac[8], wc[8];
    #pragma unroll
    for (int t=0;t<8;t++){ bac[t] = b_att[t*16 + sl]; wc[t] = Wsc[t*16 + sl]; }
    float b0 = bsc[0];
    for (int r=0;r<4;r++){
        int row = row0 + rbase + r;
        if (row >= n_rows) continue;
        float p = 0.f;
        #pragma unroll
        for (int t=0;t<8;t++) p += tanhf(acc[t][r] + bac[t]) * wc[t];
        p += __shfl_xor(p,1); p += __shfl_xor(p,2); p += __shfl_xor(p,4); p += __shfl_xor(p,8);
        if (sl == 0)
            scores[row] = (notsink[row] == 0) ? (p + b0) : -INFINITY;
    }
}

// ---------------- softmax-pool over sinks (no max: |score| <= ~5) ----------------

__global__ void k_pool1(const u16* __restrict__ h, const float* __restrict__ scores,
                        float* accum, float* part, int N){
    __shared__ float sh[256];
    __shared__ float sw[256];
    int tid = threadIdx.x;
    int col = tid & 127, grp = tid >> 7;
    float acc = 0.f, wsum = 0.f;
    for (int n = blockIdx.x*2 + grp; n < N; n += 512){
        float s = scores[n];
        if (s > -1e30f){
            float w = expf(s);
            acc += w * bf2f(h[(size_t)n*128 + col]);
            if (col == 0) wsum += w;
        }
    }
    sh[tid] = acc; sw[tid] = wsum; __syncthreads();
    if (tid < 128) sw[tid] += sw[tid+128];
    __syncthreads();
    for (int d=64; d>0; d>>=1){ if (tid < d) sw[tid] += sw[tid+d]; __syncthreads(); }
    if (tid < 128) atomicAdd(&accum[col], sh[tid] + sh[tid+128]);
    if (tid == 0) part[blockIdx.x] = sw[0];
}

__global__ void k_pool2(const float* __restrict__ part, const float* __restrict__ accum,
                        float* __restrict__ out){
    __shared__ float sh[256];
    int tid = threadIdx.x;
    sh[tid] = part[tid]; __syncthreads();
    for (int d=128; d>0; d>>=1){ if (tid < d) sh[tid] += sh[tid+d]; __syncthreads(); }
    if (tid < 128) out[tid] = accum[tid] / sh[0];
}

// ---------------- host launch ----------------

extern "C" void kernel_launch(void* const* d_in, const int* in_sizes, int n_in,
                              void* d_out, int out_size, void* d_ws, size_t ws_size,
                              hipStream_t stream)
{
    const float* node_feats = (const float*)d_in[0];
    const int* src     = (const int*)d_in[1];
    const int* dst     = (const int*)d_in[2];
    const float* W_in    = (const float*)d_in[3];
    const float* b_in    = (const float*)d_in[4];
    const float* Ws      = (const float*)d_in[5];
    const float* bs      = (const float*)d_in[6];
    const float* Wn      = (const float*)d_in[7];
    const float* bn      = (const float*)d_in[8];
    const float* Wg      = (const float*)d_in[9];
    const float* bg      = (const float*)d_in[10];
    const float* gamma   = (const float*)d_in[11];
    const float* beta    = (const float*)d_in[12];
    const float* W_att   = (const float*)d_in[13];
    const float* b_att   = (const float*)d_in[14];
    const float* W_score = (const float*)d_in[15];
    const float* b_score = (const float*)d_in[16];

    const int N = in_sizes[0] / 128;
    const int E = in_sizes[1];

    char* w = (char*)d_ws;
    auto alloc = [&](size_t bytes)->char* {
        char* p = w; w += (bytes + 255) & ~(size_t)255; return p;
    };
    u16* WT_in  = (u16*)alloc(128*128*2);
    u16* WT_s   = (u16*)alloc(3*128*128*2);
    u16* WT_n   = (u16*)alloc(3*128*128*2);
    u16* WT_g   = (u16*)alloc(3*128*256*2);
    u16* WT_att = (u16*)alloc(128*128*2);
    // zeroed region: cnt, notsink, emb_accum (contiguous)
    int* cnt      = (int*)alloc((size_t)N*4);
    int* notsink  = (int*)alloc((size_t)N*4);
    float* emb_accum = (float*)alloc(128*4);
    size_t zero_bytes = (size_t)((char*)(emb_accum + 128) - (char*)cnt);
    int* pos      = (int*)alloc((size_t)E*4);
    int* row_ptr  = (int*)alloc((size_t)N*4);
    int* blocksum = (int*)alloc(1024*4);
    int* csr_src  = (int*)alloc((size_t)E*4);
    float* inv_deg = (float*)alloc((size_t)N*4);
    float* haspred = (float*)alloc((size_t)N*4);
    float* scores  = (float*)alloc((size_t)N*4);
    float* part    = (float*)alloc(256*4);
    u16* buf0 = (u16*)alloc((size_t)N*128*2);   // h ping
    u16* buf1 = (u16*)alloc((size_t)N*128*2);   // h pong
    u16* bufn = (u16*)alloc((size_t)N*128*2);   // neigh

    float* h_out   = (float*)d_out;
    float* emb_out = h_out + (size_t)N*128;

    hipMemsetAsync(cnt, 0, zero_bytes, stream);

    k_wt_all<<<(229376+255)/256, 256, 0, stream>>>(W_in, Ws, Wn, Wg, W_att,
                                                   WT_in, WT_s, WT_n, WT_g, WT_att);

    k_count<<<(E+255)/256, 256, 0, stream>>>(src, dst, cnt, notsink, pos, E);

    int nb = (N + 1023) / 1024;
    k_scan1<<<nb, 256, 0, stream>>>(cnt, blocksum, N);
    k_scan2<<<1, 256, 0, stream>>>(blocksum, nb);
    k_scan3<<<nb, 256, 0, stream>>>(cnt, blocksum, row_ptr, inv_deg, haspred, N);
    k_place<<<(E+255)/256, 256, 0, stream>>>(src, dst, row_ptr, pos, csr_src, E);

    int gblk = (N + 63) / 64;
    int nblk = (N + 15) / 16;

    k_gemm_in<<<gblk, 256, 0, stream>>>(node_feats, WT_in, b_in, buf0, N);

    u16* hin = buf0;
    for (int i=0;i<3;i++){
        k_neigh<<<nblk, 256, 0, stream>>>(hin, row_ptr, cnt, inv_deg, csr_src, bufn, N);
        u16* hb  = (hin == buf0) ? buf1 : buf0;
        float* hf = (i == 2) ? h_out : nullptr;
        k_layer<<<gblk, 256, 0, stream>>>(hin, bufn,
                                          WT_s + i*16384, WT_n + i*16384, WT_g + i*32768,
                                          bs + i*128, bn + i*128, bg + i*128,
                                          gamma + i*128, beta + i*128, haspred,
                                          hb, hf, N);
        hin = hb;
    }

    k_gemm_att<<<gblk, 256, 0, stream>>>(hin, WT_att, b_att, W_score, b_score,
                                         notsink, scores, N);
    k_pool1<<<256, 256, 0, stream>>>(hin, scores, emb_accum, part, N);
    k_pool2<<<1, 256, 0, stream>>>(part, emb_accum, emb_out);

    (void)n_in; (void)out_size; (void)ws_size;
}